// Round 1
// 784.258 us; speedup vs baseline: 1.0251x; 1.0251x over previous
//
#include <hip/hip_runtime.h>

#define MNODES 50000
#define M_PAD  50048          // 391 * 128
#define NEDGES 800000
#define DIN    128
#define DD     256
#define D2     512
#define NLAYERS 3
#define BN_EPS 1e-5f
#define NREP   16             // stats replica rows (contention spreader)

typedef unsigned short ushort_t;
typedef __bf16 v8bf __attribute__((ext_vector_type(8)));
typedef unsigned short v8us __attribute__((ext_vector_type(8)));
typedef float  v4f  __attribute__((ext_vector_type(4)));

#define GLOBAL_AS __attribute__((address_space(1)))
#define LDS_AS    __attribute__((address_space(3)))

__device__ __forceinline__ float bf2f(ushort_t u) {
    unsigned x = ((unsigned)u) << 16;
    return __uint_as_float(x);
}
__device__ __forceinline__ ushort_t f2bf(float f) {
    unsigned u = __float_as_uint(f);
    u += 0x7FFF + ((u >> 16) & 1);   // RNE
    return (ushort_t)(u >> 16);
}
__device__ __forceinline__ void async16(const ushort_t* g, ushort_t* l) {
    __builtin_amdgcn_global_load_lds((const GLOBAL_AS unsigned int*)g,
                                     (LDS_AS unsigned int*)l, 16, 0, 0);
}
// raw barrier: no vmcnt drain (DMA loads stay in flight); compiler has already
// waited lgkmcnt for MFMA operand consumption before we get here
#define BARRIER() asm volatile("s_barrier" ::: "memory")
#define VMWAIT8() asm volatile("s_waitcnt vmcnt(8)" ::: "memory")
#define VMWAIT4() asm volatile("s_waitcnt vmcnt(4)" ::: "memory")
#define VMWAIT0() asm volatile("s_waitcnt vmcnt(0)" ::: "memory")
#define LGKM0()   asm volatile("s_waitcnt lgkmcnt(0)" ::: "memory")

// ---------------- fused prep ----------------
#define R0 (M_PAD * DIN)                       // 6406144
#define RW (DIN * DD + 2 * NLAYERS * DD * D2)  // 819200
#define NSTATZ (NREP * D2 * 2 + NREP * DD * 2) // 24576 floats (contiguous slabs)
__global__ void k_prep_all(const float* __restrict__ pre, ushort_t* __restrict__ preb,
                           const float* __restrict__ W0, const float* __restrict__ W1,
                           const float* __restrict__ W2,
                           ushort_t* __restrict__ W0T, ushort_t* __restrict__ W1T,
                           ushort_t* __restrict__ W2T,
                           float* __restrict__ caf, float* __restrict__ ccf,
                           float* __restrict__ statz, int* __restrict__ deg) {
    int i = blockIdx.x * blockDim.x + threadIdx.x;
    if (i < R0) {
        int row = i >> 7;
        preb[i] = f2bf(row < MNODES ? pre[i] : 0.f);
        return;
    }
    int j = i - R0;
    if (j < RW) {
        if (j < DIN * DD) {
            int n = j >> 7, k = j & 127;
            W0T[j] = f2bf(W0[k * DD + n]);
        } else if (j < DIN * DD + NLAYERS * DD * D2) {
            int j2 = j - DIN * DD;
            int l = j2 >> 17, off = j2 & 131071;
            int n = off >> 8, k = off & 255;      // K=256, N=512
            W1T[(size_t)l * 131072 + off] = f2bf(W1[(size_t)l * 131072 + k * D2 + n]);
        } else {
            int j2 = j - DIN * DD - NLAYERS * DD * D2;
            int l = j2 >> 17, off = j2 & 131071;
            int n = off >> 9, k = off & 511;      // K=512, N=256
            W2T[(size_t)l * 131072 + off] = f2bf(W2[(size_t)l * 131072 + k * DD + n]);
        }
        return;
    }
    j -= RW;
    if (j < 256) { caf[j] = 1.f; ccf[j] = 0.f; return; }
    j -= 256;
    if (j < NSTATZ) { statz[j] = 0.f; return; }
    j -= NSTATZ;
    if (j < MNODES) deg[j] = 0;
}

// ---------------- CSR build ----------------
__global__ void k_hist(const int* __restrict__ ei, int* __restrict__ deg) {
    int e = blockIdx.x * blockDim.x + threadIdx.x;
    if (e < NEDGES) atomicAdd(&deg[ei[e * 2 + 1]], 1);
}
__global__ void k_scan1(const int* __restrict__ deg, int* __restrict__ rowptr,
                        int* __restrict__ bsum, int n) {
    __shared__ int tmp[256];
    int tid = threadIdx.x;
    int i = blockIdx.x * 256 + tid;
    int v = (i < n) ? deg[i] : 0;
    tmp[tid] = v;
    __syncthreads();
    #pragma unroll
    for (int off = 1; off < 256; off <<= 1) {
        int t = (tid >= off) ? tmp[tid - off] : 0;
        __syncthreads();
        tmp[tid] += t;
        __syncthreads();
    }
    if (i < n) rowptr[i + 1] = tmp[tid];
    if (tid == 255) bsum[blockIdx.x] = tmp[255];
}
__global__ __launch_bounds__(256)
void k_scan2(int* __restrict__ bsum, int nb) {
    __shared__ int tmp[256];
    int tid = threadIdx.x;
    int v = (tid < nb) ? bsum[tid] : 0;
    tmp[tid] = v;
    __syncthreads();
    #pragma unroll
    for (int off = 1; off < 256; off <<= 1) {
        int t = (tid >= off) ? tmp[tid - off] : 0;
        __syncthreads();
        tmp[tid] += t;
        __syncthreads();
    }
    if (tid < nb) bsum[tid] = tmp[tid] - v;
}
__global__ void k_scan3(const int* __restrict__ deg, const int* __restrict__ bsum,
                        int* __restrict__ rowptr, int* __restrict__ cursor, int n) {
    int i = blockIdx.x * 256 + threadIdx.x;
    if (i == 0) rowptr[0] = 0;
    if (i < n) {
        int incl = rowptr[i + 1] + bsum[i >> 8];
        rowptr[i + 1] = incl;
        cursor[i] = incl - deg[i];
    }
}
__global__ void k_fill(const int* __restrict__ ei, int* __restrict__ cursor,
                       int* __restrict__ col) {
    int e = blockIdx.x * blockDim.x + threadIdx.x;
    if (e < NEDGES) {
        int pos = atomicAdd(&cursor[ei[e * 2 + 1]], 1);
        col[pos] = ei[e * 2];
    }
}

// ---------------- gather: out = ca*(x[n] + sum x[src]) + (deg+1)*cc ----------
__global__ void k_gather(const int* __restrict__ rowptr, const int* __restrict__ col,
                         const ushort_t* __restrict__ x, const float* __restrict__ ca,
                         const float* __restrict__ cc, ushort_t* __restrict__ out) {
    int node = blockIdx.x * 4 + (threadIdx.x >> 6);
    int lane = threadIdx.x & 63;
    if (node >= MNODES) return;
    const ushort4* xp = (const ushort4*)x;
    ushort4 v = xp[(size_t)node * 64 + lane];
    float a0 = bf2f(v.x), a1 = bf2f(v.y), a2 = bf2f(v.z), a3 = bf2f(v.w);
    int s = rowptr[node], e = rowptr[node + 1];
    int i = s;
    for (; i + 7 < e; i += 8) {       // 8 loads in flight
        ushort4 u[8];
        #pragma unroll
        for (int j = 0; j < 8; j++) u[j] = xp[(size_t)col[i + j] * 64 + lane];
        #pragma unroll
        for (int j = 0; j < 8; j++) {
            a0 += bf2f(u[j].x); a1 += bf2f(u[j].y);
            a2 += bf2f(u[j].z); a3 += bf2f(u[j].w);
        }
    }
    for (; i < e; i++) {
        ushort4 u = xp[(size_t)col[i] * 64 + lane];
        a0 += bf2f(u.x); a1 += bf2f(u.y); a2 += bf2f(u.z); a3 += bf2f(u.w);
    }
    int c = lane * 4;
    float dn = (float)(e - s) + 1.0f;
    ushort4 o;
    o.x = f2bf(ca[c + 0] * a0 + dn * cc[c + 0]);
    o.y = f2bf(ca[c + 1] * a1 + dn * cc[c + 1]);
    o.z = f2bf(ca[c + 2] * a2 + dn * cc[c + 2]);
    o.w = f2bf(ca[c + 3] * a3 + dn * cc[c + 3]);
    ((ushort4*)out)[(size_t)node * 64 + lane] = o;
}

// ---------------- BN coeffs: fold NREP replicas, re-zero them ----------------
__global__ void k_coeffs(float* __restrict__ sums, float* __restrict__ sumsq,
                         const float* __restrict__ g, const float* __restrict__ beta,
                         float* __restrict__ ca, float* __restrict__ cc,
                         float2* __restrict__ cacc, int n) {
    int c = blockIdx.x * blockDim.x + threadIdx.x;
    if (c >= n) return;
    float s = 0.f, q = 0.f;
    #pragma unroll
    for (int r = 0; r < NREP; r++) {
        s += sums[r * n + c];  sums[r * n + c]  = 0.f;
        q += sumsq[r * n + c]; sumsq[r * n + c] = 0.f;
    }
    float mean = s * (1.0f / MNODES);
    float var  = q * (1.0f / MNODES) - mean * mean;
    float a    = g[c] * rsqrtf(var + BN_EPS);
    float b    = beta[c] - a * mean;
    ca[c] = a;
    cc[c] = b;
    if (cacc) cacc[c] = make_float2(a, b);
}

// ---------------- final: d_out = ca*h + cc (fp32) ----------------
__global__ void k_apply_out(const ushort_t* __restrict__ h, const float* __restrict__ ca,
                            const float* __restrict__ cc, float* __restrict__ out) {
    int i = blockIdx.x * blockDim.x + threadIdx.x;
    if (i >= MNODES * 64) return;
    int c = (i & 63) * 4;
    ushort4 v = ((const ushort4*)h)[i];
    float4 o;
    o.x = ca[c + 0] * bf2f(v.x) + cc[c + 0];
    o.y = ca[c + 1] * bf2f(v.y) + cc[c + 1];
    o.z = ca[c + 2] * bf2f(v.z) + cc[c + 2];
    o.w = ca[c + 3] * bf2f(v.w) + cc[c + 3];
    ((float4*)out)[i] = o;
}

// ---------------- pipelined bf16 MFMA GEMM, 128x128 tile, BK=32 --------------
// 3-stage LDS ring, 2-step vmcnt lookahead (tile t+1 has been in flight for 2
// full K-steps when we wait on it). DMA staging via global_load_lds with the
// chunk-XOR swizzle: LDS row r (32 ushort), slot s holds global chunk
// s ^ ((r>>2)&3) -> fragment ds_read_b128 is 2-way max (free).
// XCD-chunked bijective block swizzle: blocks sharing an A-panel land on the
// same XCD for L2 reuse.
// FUSE_BN: A-fragments get relu(ca*a+cc) applied in-register (coeffs staged to
// LDS so vmcnt counting is undisturbed) -> replaces the k_prerelu pass.
// Stats: per-wave shfl reduce -> LDS cross-wave reduce -> NREP-replica slab
// (atomic contention per address ~24 instead of 782).
template<int DO_STATS, int RES, int FUSE_BN>
__global__ __launch_bounds__(256, 3)
void k_gemm_bf(const ushort_t* __restrict__ A, const ushort_t* __restrict__ WT,
               const float* __restrict__ bias,
               const ushort_t* resid, const float* __restrict__ r_ca,
               const float* __restrict__ r_cc, const float2* __restrict__ cacc,
               ushort_t* out, float* __restrict__ sums, float* __restrict__ sumsq,
               int M, int K, int N) {
    __shared__ __align__(16) ushort_t As[3][128 * 32];
    __shared__ __align__(16) ushort_t Bs[3][128 * 32];
    __shared__ __align__(16) float2 cacc_lds[512];
    const int tid = threadIdx.x;
    const int w = tid >> 6, lane = tid & 63;
    const int wm = w >> 1, wn = w & 1;
    const int quad = lane >> 4, l15 = lane & 15;

    // bijective XCD-chunked swizzle (nwg not necessarily %8==0)
    const int nxb = N >> 7;                         // 2 or 4 (power of two)
    const int nwg = nxb * (int)gridDim.y;
    const int orig = (int)blockIdx.y * nxb + (int)blockIdx.x;
    const int qq = nwg >> 3, rr = nwg & 7, xc = orig & 7, oi = orig >> 3;
    const int swz = (xc < rr ? xc * (qq + 1) : rr * (qq + 1) + (xc - rr) * qq) + oi;
    const int bx = swz & (nxb - 1);
    const int by = (nxb == 4) ? (swz >> 2) : (swz >> 1);
    const int m0 = by * 128, n0 = bx * 128;

    // FUSE_BN: stage interleaved (ca,cc) per-k into LDS (keeps loop vmcnt clean)
    if (FUSE_BN) {
        for (int k2 = tid; k2 < K; k2 += 256) cacc_lds[k2] = cacc[k2];
        LGKM0();
    }

    // staging: 8 issues of 16 rows per tile (A and B each); wave w does issues
    // {w, w+4}. lane i covers row rbase+(i>>2), slot i&3.
    const ushort_t* aA[2];
    const ushort_t* aB[2];
    int aoff[2];
    #pragma unroll
    for (int j = 0; j < 2; j++) {
        int ii = j * 4 + w;
        int r = ii * 16 + (lane >> 2);
        int cg = (lane & 3) ^ ((r >> 2) & 3);
        aA[j] = A  + (size_t)(m0 + r) * K + cg * 8;
        aB[j] = WT + (size_t)(n0 + r) * K + cg * 8;
        aoff[j] = ii * 512;              // 16 rows * 32 ushort
    }

    v4f acc[4][4];
    #pragma unroll
    for (int i = 0; i < 4; i++)
        #pragma unroll
        for (int j = 0; j < 4; j++)
            acc[i][j] = (v4f){0.f, 0.f, 0.f, 0.f};

    const int nk = K >> 5;               // >= 4 for all our shapes

    // prologue: issue tiles 0,1,2 (12 DMAs/wave); drain tile 0 only
    #pragma unroll
    for (int s = 0; s < 3; s++) {
        #pragma unroll
        for (int j = 0; j < 2; j++) {
            async16(aA[j] + s * 32, &As[s][aoff[j]]);
            async16(aB[j] + s * 32, &Bs[s][aoff[j]]);
        }
    }
    VMWAIT8();
    BARRIER();

    const int sl = quad ^ ((l15 >> 2) & 3);
    int cur = 0;
    for (int t = 0; t < nk; t++) {
        const ushort_t* Ab = As[cur];
        const ushort_t* Bb = Bs[cur];
        v8bf af[4], bfr[4];
        #pragma unroll
        for (int tt = 0; tt < 4; tt++) {
            int m_l = wm * 64 + tt * 16 + l15;
            af[tt]  = *(const v8bf*)&Ab[m_l * 32 + sl * 8];
            int n_l = wn * 64 + tt * 16 + l15;
            bfr[tt] = *(const v8bf*)&Bb[n_l * 32 + sl * 8];
        }
        if (FUSE_BN) {
            // fragment element j of af corresponds to global k = t*32 + quad*8 + j
            const float* cb = (const float*)&cacc_lds[(t << 5) + (quad << 3)];
            float cav[8], ccv[8];
            #pragma unroll
            for (int j = 0; j < 8; j++) { cav[j] = cb[2 * j]; ccv[j] = cb[2 * j + 1]; }
            #pragma unroll
            for (int tt = 0; tt < 4; tt++) {
                v8us au = *(v8us*)&af[tt];
                v8us ou;
                #pragma unroll
                for (int j = 0; j < 8; j++) {
                    float h = bf2f(au[j]);
                    ou[j] = f2bf(fmaxf(fmaf(cav[j], h, ccv[j]), 0.f));
                }
                af[tt] = *(v8bf*)&ou;
            }
        }
        #pragma unroll
        for (int mt = 0; mt < 4; mt++)
            #pragma unroll
            for (int nt = 0; nt < 4; nt++)
                acc[mt][nt] = __builtin_amdgcn_mfma_f32_16x16x32_bf16(
                    af[mt], bfr[nt], acc[mt][nt], 0, 0, 0);
        if (t == nk - 1) break;
        BARRIER();                        // all waves done reading slot cur
        if (t + 3 < nk) {
            int kl = (t + 3) * 32;
            #pragma unroll
            for (int j = 0; j < 2; j++) {
                async16(aA[j] + kl, &As[cur][aoff[j]]);
                async16(aB[j] + kl, &Bs[cur][aoff[j]]);
            }
            VMWAIT8();                    // drain t+1 (in flight 2 steps); t+2,t+3 stay
        } else if (t + 2 < nk) {
            VMWAIT4();                    // drain t+1; t+2 stays in flight
        } else {
            VMWAIT0();                    // drain last tile
        }
        BARRIER();                        // everyone's tile t+1 DMA visible
        cur = (cur == 2) ? 0 : cur + 1;
    }

    // epilogue: bias (+ lazy-BN residual) -> bf16 store + fused column stats
    const int mlim = M - m0;
    float s_sum[4] = {0.f, 0.f, 0.f, 0.f}, s_sq[4] = {0.f, 0.f, 0.f, 0.f};
    #pragma unroll
    for (int nt = 0; nt < 4; nt++) {
        int colg = n0 + wn * 64 + nt * 16 + l15;
        float bia = bias[colg];
        float rca = 0.f, rcc = 0.f;
        if (RES) { rca = r_ca[colg]; rcc = r_cc[colg]; }
        #pragma unroll
        for (int mt = 0; mt < 4; mt++) {
            int rbase = wm * 64 + mt * 16 + quad * 4;
            #pragma unroll
            for (int r = 0; r < 4; r++) {
                int rl = rbase + r;
                if (rl < mlim) {
                    size_t idx = (size_t)(m0 + rl) * N + colg;
                    float v = acc[mt][nt][r] + bia;
                    if (RES) v += rca * bf2f(resid[idx]) + rcc;
                    out[idx] = f2bf(v);
                    if (DO_STATS) { s_sum[nt] += v; s_sq[nt] += v * v; }
                }
            }
        }
    }
    if (DO_STATS) {
        #pragma unroll
        for (int nt = 0; nt < 4; nt++) {
            s_sum[nt] += __shfl_xor(s_sum[nt], 16); s_sq[nt] += __shfl_xor(s_sq[nt], 16);
            s_sum[nt] += __shfl_xor(s_sum[nt], 32); s_sq[nt] += __shfl_xor(s_sq[nt], 32);
        }
        // cross-wave reduce in LDS (reuse As), then NREP-replica global adds
        float* red = (float*)&As[0][0];   // 512 floats: [wm][{sum,sq}][128 cols]
        BARRIER();                        // all frag reads retired before overwrite
        if (quad == 0) {
            #pragma unroll
            for (int nt = 0; nt < 4; nt++) {
                int cb = wn * 64 + nt * 16 + l15;
                red[wm * 256 + cb]       = s_sum[nt];
                red[wm * 256 + 128 + cb] = s_sq[nt];
            }
        }
        LGKM0();
        BARRIER();
        if (tid < 128) {
            float s = red[tid]       + red[256 + tid];
            float q = red[128 + tid] + red[384 + tid];
            int rep = by & (NREP - 1);
            atomicAdd(&sums[rep * N + n0 + tid], s);
            atomicAdd(&sumsq[rep * N + n0 + tid], q);
        }
    }
}

extern "C" void kernel_launch(void* const* d_in, const int* in_sizes, int n_in,
                              void* d_out, int out_size, void* d_ws, size_t ws_size,
                              hipStream_t stream) {
    const float* pre   = (const float*)d_in[0];
    const int*   ei    = (const int*)d_in[1];
    const float* W0    = (const float*)d_in[2];
    const float* b0    = (const float*)d_in[3];
    const float* W1    = (const float*)d_in[4];
    const float* b1    = (const float*)d_in[5];
    const float* g1    = (const float*)d_in[6];
    const float* beta1 = (const float*)d_in[7];
    const float* W2    = (const float*)d_in[8];
    const float* b2    = (const float*)d_in[9];
    const float* gf    = (const float*)d_in[10];
    const float* betaf = (const float*)d_in[11];

    char* p = (char*)d_ws;
    ushort_t* preb = (ushort_t*)p; p += (size_t)M_PAD * DIN * 2;
    ushort_t* ACT1 = (ushort_t*)p; p += (size_t)M_PAD * DD * 2;
    ushort_t* ACT2 = (ushort_t*)p; p += (size_t)M_PAD * DD * 2;
    ushort_t* H1   = (ushort_t*)p; p += (size_t)M_PAD * D2 * 2;
    ushort_t* W0T  = (ushort_t*)p; p += (size_t)DIN * DD * 2;
    ushort_t* W1T  = (ushort_t*)p; p += (size_t)NLAYERS * DD * D2 * 2;
    ushort_t* W2T  = (ushort_t*)p; p += (size_t)NLAYERS * D2 * DD * 2;
    // stats replica slabs — must stay contiguous (prep zeroes them as one range)
    float* sums1  = (float*)p; p += (size_t)NREP * D2 * 4;
    float* sumsq1 = (float*)p; p += (size_t)NREP * D2 * 4;
    float* sumsF  = (float*)p; p += (size_t)NREP * DD * 4;
    float* sumsqF = (float*)p; p += (size_t)NREP * DD * 4;
    float* ca1    = (float*)p; p += D2 * 4;
    float* cc1    = (float*)p; p += D2 * 4;
    float* caf    = (float*)p; p += DD * 4;
    float* ccf    = (float*)p; p += DD * 4;
    float2* cacc1 = (float2*)p; p += D2 * 8;
    int* deg    = (int*)p; p += (size_t)MNODES * 4;
    int* rowptr = (int*)p; p += (size_t)(MNODES + 1) * 4;
    int* cursor = (int*)p; p += (size_t)MNODES * 4;
    int* colx   = (int*)p; p += (size_t)NEDGES * 4;
    int* bsum   = (int*)p; p += 256 * 4;

    dim3 blk(256);
    const int mb = (MNODES + 127) / 128;        // 391
    const int nsb = (MNODES + 255) / 256;       // 196

    const int prep_total = R0 + RW + 256 + NSTATZ + MNODES;
    k_prep_all<<<(prep_total + 255) / 256, blk, 0, stream>>>(
        pre, preb, W0, W1, W2, W0T, W1T, W2T, caf, ccf, sums1, deg);

    k_hist<<<(NEDGES + 255) / 256, blk, 0, stream>>>(ei, deg);
    k_scan1<<<nsb, blk, 0, stream>>>(deg, rowptr, bsum, MNODES);
    k_scan2<<<1, blk, 0, stream>>>(bsum, nsb);
    k_scan3<<<nsb, blk, 0, stream>>>(deg, bsum, rowptr, cursor, MNODES);
    k_fill<<<(NEDGES + 255) / 256, blk, 0, stream>>>(ei, cursor, colx);

    // X0 = pre @ W0 + b0  -> ACT2
    k_gemm_bf<0, 0, 0><<<dim3(DD / 128, mb), blk, 0, stream>>>(
        preb, W0T, b0, nullptr, nullptr, nullptr, nullptr,
        ACT2, nullptr, nullptr, MNODES, DIN, DD);

    for (int l = 0; l < NLAYERS; l++) {
        // ACT1 = caf*(ACT2[n] + sum ACT2[src]) + (deg+1)*ccf
        k_gather<<<(MNODES + 3) / 4, blk, 0, stream>>>(rowptr, colx, ACT2, caf, ccf, ACT1);

        // H1 = ACT1 @ W1 + b1 (raw, pre-BN), fused column stats
        k_gemm_bf<1, 0, 0><<<dim3(D2 / 128, mb), blk, 0, stream>>>(
            ACT1, W1T + (size_t)l * DD * D2, b1 + (size_t)l * D2,
            nullptr, nullptr, nullptr, nullptr,
            H1, sums1, sumsq1, MNODES, DD, D2);
        k_coeffs<<<2, blk, 0, stream>>>(sums1, sumsq1, g1 + (size_t)l * D2,
                                        beta1 + (size_t)l * D2, ca1, cc1, cacc1, D2);

        // ACT2 = relu(bn1(H1)) @ W2 + b2 + bn_prev(ACT2)
        // (BN1+ReLU fused into A-fragment path; in place; fused stats)
        k_gemm_bf<1, 1, 1><<<dim3(DD / 128, mb), blk, 0, stream>>>(
            H1, W2T + (size_t)l * D2 * DD, b2 + (size_t)l * DD,
            ACT2, caf, ccf, cacc1,
            ACT2, sumsF, sumsqF, MNODES, D2, DD);
        k_coeffs<<<1, blk, 0, stream>>>(sumsF, sumsqF, gf + (size_t)l * DD,
                                        betaf + (size_t)l * DD, caf, ccf, nullptr, DD);
    }

    // d_out = caf*ACT2 + ccf  (fp32)
    k_apply_out<<<(MNODES * 64 + 255) / 256, blk, 0, stream>>>(ACT2, caf, ccf, (float*)d_out);
}

// Round 2
// 749.355 us; speedup vs baseline: 1.0728x; 1.0466x over previous
//
#include <hip/hip_runtime.h>

#define MNODES 50000
#define M_PAD  50048          // 391 * 128
#define NEDGES 800000
#define DIN    128
#define DD     256
#define D2     512
#define NLAYERS 3
#define BN_EPS 1e-5f
#define NREP   16             // stats replica rows (contention spreader)

typedef unsigned short ushort_t;
typedef __bf16 v8bf __attribute__((ext_vector_type(8)));
typedef unsigned short v8us __attribute__((ext_vector_type(8)));
typedef float  v4f  __attribute__((ext_vector_type(4)));

#define GLOBAL_AS __attribute__((address_space(1)))
#define LDS_AS    __attribute__((address_space(3)))

__device__ __forceinline__ float bf2f(ushort_t u) {
    unsigned x = ((unsigned)u) << 16;
    return __uint_as_float(x);
}
__device__ __forceinline__ ushort_t f2bf(float f) {
    unsigned u = __float_as_uint(f);
    u += 0x7FFF + ((u >> 16) & 1);   // RNE
    return (ushort_t)(u >> 16);
}
__device__ __forceinline__ void async16(const ushort_t* g, ushort_t* l) {
    __builtin_amdgcn_global_load_lds((const GLOBAL_AS unsigned int*)g,
                                     (LDS_AS unsigned int*)l, 16, 0, 0);
}
// raw barrier: no vmcnt drain (DMA loads stay in flight); compiler has already
// waited lgkmcnt for MFMA operand consumption before we get here
#define BARRIER() asm volatile("s_barrier" ::: "memory")
#define VMWAIT4() asm volatile("s_waitcnt vmcnt(4)" ::: "memory")
#define VMWAIT0() asm volatile("s_waitcnt vmcnt(0)" ::: "memory")
#define LGKM0()   asm volatile("s_waitcnt lgkmcnt(0)" ::: "memory")

// ---------------- fused prep ----------------
#define R0 (M_PAD * DIN)                       // 6406144
#define RW (DIN * DD + 2 * NLAYERS * DD * D2)  // 819200
#define NSTATZ (NREP * D2 * 2 + NREP * DD * 2) // 24576 floats (contiguous slabs)
__global__ void k_prep_all(const float* __restrict__ pre, ushort_t* __restrict__ preb,
                           const float* __restrict__ W0, const float* __restrict__ W1,
                           const float* __restrict__ W2,
                           ushort_t* __restrict__ W0T, ushort_t* __restrict__ W1T,
                           ushort_t* __restrict__ W2T,
                           float* __restrict__ caf, float* __restrict__ ccf,
                           float* __restrict__ statz, int* __restrict__ deg) {
    int i = blockIdx.x * blockDim.x + threadIdx.x;
    if (i < R0) {
        int row = i >> 7;
        preb[i] = f2bf(row < MNODES ? pre[i] : 0.f);
        return;
    }
    int j = i - R0;
    if (j < RW) {
        if (j < DIN * DD) {
            int n = j >> 7, k = j & 127;
            W0T[j] = f2bf(W0[k * DD + n]);
        } else if (j < DIN * DD + NLAYERS * DD * D2) {
            int j2 = j - DIN * DD;
            int l = j2 >> 17, off = j2 & 131071;
            int n = off >> 8, k = off & 255;      // K=256, N=512
            W1T[(size_t)l * 131072 + off] = f2bf(W1[(size_t)l * 131072 + k * D2 + n]);
        } else {
            int j2 = j - DIN * DD - NLAYERS * DD * D2;
            int l = j2 >> 17, off = j2 & 131071;
            int n = off >> 9, k = off & 511;      // K=512, N=256
            W2T[(size_t)l * 131072 + off] = f2bf(W2[(size_t)l * 131072 + k * DD + n]);
        }
        return;
    }
    j -= RW;
    if (j < 256) { caf[j] = 1.f; ccf[j] = 0.f; return; }
    j -= 256;
    if (j < NSTATZ) { statz[j] = 0.f; return; }
    j -= NSTATZ;
    if (j < MNODES) deg[j] = 0;
}

// ---------------- CSR build ----------------
__global__ void k_hist(const int* __restrict__ ei, int* __restrict__ deg) {
    int e = blockIdx.x * blockDim.x + threadIdx.x;
    if (e < NEDGES) atomicAdd(&deg[ei[e * 2 + 1]], 1);
}
__global__ void k_scan1(const int* __restrict__ deg, int* __restrict__ rowptr,
                        int* __restrict__ bsum, int n) {
    __shared__ int tmp[256];
    int tid = threadIdx.x;
    int i = blockIdx.x * 256 + tid;
    int v = (i < n) ? deg[i] : 0;
    tmp[tid] = v;
    __syncthreads();
    #pragma unroll
    for (int off = 1; off < 256; off <<= 1) {
        int t = (tid >= off) ? tmp[tid - off] : 0;
        __syncthreads();
        tmp[tid] += t;
        __syncthreads();
    }
    if (i < n) rowptr[i + 1] = tmp[tid];
    if (tid == 255) bsum[blockIdx.x] = tmp[255];
}
__global__ __launch_bounds__(256)
void k_scan2(int* __restrict__ bsum, int nb) {
    __shared__ int tmp[256];
    int tid = threadIdx.x;
    int v = (tid < nb) ? bsum[tid] : 0;
    tmp[tid] = v;
    __syncthreads();
    #pragma unroll
    for (int off = 1; off < 256; off <<= 1) {
        int t = (tid >= off) ? tmp[tid - off] : 0;
        __syncthreads();
        tmp[tid] += t;
        __syncthreads();
    }
    if (tid < nb) bsum[tid] = tmp[tid] - v;
}
__global__ void k_scan3(const int* __restrict__ deg, const int* __restrict__ bsum,
                        int* __restrict__ rowptr, int* __restrict__ cursor, int n) {
    int i = blockIdx.x * 256 + threadIdx.x;
    if (i == 0) rowptr[0] = 0;
    if (i < n) {
        int incl = rowptr[i + 1] + bsum[i >> 8];
        rowptr[i + 1] = incl;
        cursor[i] = incl - deg[i];
    }
}
__global__ void k_fill(const int* __restrict__ ei, int* __restrict__ cursor,
                       int* __restrict__ col) {
    int e = blockIdx.x * blockDim.x + threadIdx.x;
    if (e < NEDGES) {
        int pos = atomicAdd(&cursor[ei[e * 2 + 1]], 1);
        col[pos] = ei[e * 2];
    }
}

// ---------------- gather: out = ca*(x[n] + sum x[src]) + (deg+1)*cc ----------
__global__ void k_gather(const int* __restrict__ rowptr, const int* __restrict__ col,
                         const ushort_t* __restrict__ x, const float* __restrict__ ca,
                         const float* __restrict__ cc, ushort_t* __restrict__ out) {
    int node = blockIdx.x * 4 + (threadIdx.x >> 6);
    int lane = threadIdx.x & 63;
    if (node >= MNODES) return;
    const ushort4* xp = (const ushort4*)x;
    ushort4 v = xp[(size_t)node * 64 + lane];
    float a0 = bf2f(v.x), a1 = bf2f(v.y), a2 = bf2f(v.z), a3 = bf2f(v.w);
    int s = rowptr[node], e = rowptr[node + 1];
    int i = s;
    for (; i + 7 < e; i += 8) {       // 8 loads in flight
        ushort4 u[8];
        #pragma unroll
        for (int j = 0; j < 8; j++) u[j] = xp[(size_t)col[i + j] * 64 + lane];
        #pragma unroll
        for (int j = 0; j < 8; j++) {
            a0 += bf2f(u[j].x); a1 += bf2f(u[j].y);
            a2 += bf2f(u[j].z); a3 += bf2f(u[j].w);
        }
    }
    for (; i < e; i++) {
        ushort4 u = xp[(size_t)col[i] * 64 + lane];
        a0 += bf2f(u.x); a1 += bf2f(u.y); a2 += bf2f(u.z); a3 += bf2f(u.w);
    }
    int c = lane * 4;
    float dn = (float)(e - s) + 1.0f;
    ushort4 o;
    o.x = f2bf(ca[c + 0] * a0 + dn * cc[c + 0]);
    o.y = f2bf(ca[c + 1] * a1 + dn * cc[c + 1]);
    o.z = f2bf(ca[c + 2] * a2 + dn * cc[c + 2]);
    o.w = f2bf(ca[c + 3] * a3 + dn * cc[c + 3]);
    ((ushort4*)out)[(size_t)node * 64 + lane] = o;
}

// ---------------- BN coeffs: fold NREP replicas, re-zero them ----------------
__global__ void k_coeffs(float* __restrict__ sums, float* __restrict__ sumsq,
                         const float* __restrict__ g, const float* __restrict__ beta,
                         float* __restrict__ ca, float* __restrict__ cc,
                         float2* __restrict__ cacc, int n) {
    int c = blockIdx.x * blockDim.x + threadIdx.x;
    if (c >= n) return;
    float s = 0.f, q = 0.f;
    #pragma unroll
    for (int r = 0; r < NREP; r++) {
        s += sums[r * n + c];  sums[r * n + c]  = 0.f;
        q += sumsq[r * n + c]; sumsq[r * n + c] = 0.f;
    }
    float mean = s * (1.0f / MNODES);
    float var  = q * (1.0f / MNODES) - mean * mean;
    float a    = g[c] * rsqrtf(var + BN_EPS);
    float b    = beta[c] - a * mean;
    ca[c] = a;
    cc[c] = b;
    if (cacc) cacc[c] = make_float2(a, b);
}

// ---------------- final: d_out = ca*h + cc (fp32) ----------------
__global__ void k_apply_out(const ushort_t* __restrict__ h, const float* __restrict__ ca,
                            const float* __restrict__ cc, float* __restrict__ out) {
    int i = blockIdx.x * blockDim.x + threadIdx.x;
    if (i >= MNODES * 64) return;
    int c = (i & 63) * 4;
    ushort4 v = ((const ushort4*)h)[i];
    float4 o;
    o.x = ca[c + 0] * bf2f(v.x) + cc[c + 0];
    o.y = ca[c + 1] * bf2f(v.y) + cc[c + 1];
    o.z = ca[c + 2] * bf2f(v.z) + cc[c + 2];
    o.w = ca[c + 3] * bf2f(v.w) + cc[c + 3];
    ((float4*)out)[i] = o;
}

// ---------------- pipelined bf16 MFMA GEMM, 128x128 tile, BK=32 --------------
// 2-stage LDS double-buffer (32 KB -> up to 5 blocks/CU for the non-FUSE
// variant; occupancy is the latency-hiding mechanism in this short-K regime).
// DMA staging via global_load_lds with the chunk-XOR swizzle: LDS row r
// (32 ushort), slot s holds global chunk s ^ ((r>>2)&3) -> ds_read_b128 is
// 2-way max (free). Raw s_barrier + fine vmcnt(4): tile t+2 loads stay in
// flight across barriers. XCD-chunked bijective block swizzle for L2 reuse.
// FUSE_BN: A-fragments get relu(ca*a+cc) in-register (coeffs staged to LDS,
// allocated only in that instantiation) -> replaces the k_prerelu pass.
// Stats: shfl reduce -> quad==0 atomics into NREP-replica slab.
template<int DO_STATS, int RES, int FUSE_BN>
__global__ __launch_bounds__(256, 4)
void k_gemm_bf(const ushort_t* __restrict__ A, const ushort_t* __restrict__ WT,
               const float* __restrict__ bias,
               const ushort_t* resid, const float* __restrict__ r_ca,
               const float* __restrict__ r_cc, const float2* __restrict__ cacc,
               ushort_t* out, float* __restrict__ sums, float* __restrict__ sumsq,
               int M, int K, int N) {
    __shared__ __align__(16) ushort_t As[2][128 * 32];
    __shared__ __align__(16) ushort_t Bs[2][128 * 32];
    const int tid = threadIdx.x;
    const int w = tid >> 6, lane = tid & 63;
    const int wm = w >> 1, wn = w & 1;
    const int quad = lane >> 4, l15 = lane & 15;

    // bijective XCD-chunked swizzle (nwg not necessarily %8==0)
    const int nxb = N >> 7;                         // 2 or 4 (power of two)
    const int nwg = nxb * (int)gridDim.y;
    const int orig = (int)blockIdx.y * nxb + (int)blockIdx.x;
    const int qq = nwg >> 3, rr = nwg & 7, xc = orig & 7, oi = orig >> 3;
    const int swz = (xc < rr ? xc * (qq + 1) : rr * (qq + 1) + (xc - rr) * qq) + oi;
    const int bx = swz & (nxb - 1);
    const int by = (nxb == 4) ? (swz >> 2) : (swz >> 1);
    const int m0 = by * 128, n0 = bx * 128;

    // FUSE_BN: stage interleaved (ca,cc) per-k into LDS (keeps loop vmcnt
    // clean). if constexpr so the non-FUSE variant allocates NO extra LDS.
    float2* cacc_lds = nullptr;
    if constexpr (FUSE_BN != 0) {
        __shared__ __align__(16) float2 cacc_s[512];
        cacc_lds = cacc_s;
        for (int k2 = tid; k2 < K; k2 += 256) cacc_lds[k2] = cacc[k2];
        LGKM0();
    }

    // staging: 8 issues of 16 rows per tile (A and B each); wave w does issues
    // {w, w+4}. lane i covers row rbase+(i>>2), slot i&3.
    const ushort_t* aA[2];
    const ushort_t* aB[2];
    int aoff[2];
    #pragma unroll
    for (int j = 0; j < 2; j++) {
        int ii = j * 4 + w;
        int r = ii * 16 + (lane >> 2);
        int cg = (lane & 3) ^ ((r >> 2) & 3);
        aA[j] = A  + (size_t)(m0 + r) * K + cg * 8;
        aB[j] = WT + (size_t)(n0 + r) * K + cg * 8;
        aoff[j] = ii * 512;              // 16 rows * 32 ushort
    }

    v4f acc[4][4];
    #pragma unroll
    for (int i = 0; i < 4; i++)
        #pragma unroll
        for (int j = 0; j < 4; j++)
            acc[i][j] = (v4f){0.f, 0.f, 0.f, 0.f};

    const int nk = K >> 5;               // >= 4 for all our shapes

    // prologue: issue tiles 0 and 1; drain tile 0 only
    #pragma unroll
    for (int j = 0; j < 2; j++) {
        async16(aA[j], &As[0][aoff[j]]);
        async16(aB[j], &Bs[0][aoff[j]]);
    }
    #pragma unroll
    for (int j = 0; j < 2; j++) {
        async16(aA[j] + 32, &As[1][aoff[j]]);
        async16(aB[j] + 32, &Bs[1][aoff[j]]);
    }
    VMWAIT4();
    BARRIER();

    const int sl = quad ^ ((l15 >> 2) & 3);
    for (int t = 0; t < nk; t++) {
        const ushort_t* Ab = As[t & 1];
        const ushort_t* Bb = Bs[t & 1];
        v8bf af[4], bfr[4];
        #pragma unroll
        for (int tt = 0; tt < 4; tt++) {
            int m_l = wm * 64 + tt * 16 + l15;
            af[tt]  = *(const v8bf*)&Ab[m_l * 32 + sl * 8];
            int n_l = wn * 64 + tt * 16 + l15;
            bfr[tt] = *(const v8bf*)&Bb[n_l * 32 + sl * 8];
        }
        if constexpr (FUSE_BN != 0) {
            // fragment element j of af corresponds to global k = t*32 + quad*8 + j
            const float* cb = (const float*)&cacc_lds[(t << 5) + (quad << 3)];
            float cav[8], ccv[8];
            #pragma unroll
            for (int j = 0; j < 8; j++) { cav[j] = cb[2 * j]; ccv[j] = cb[2 * j + 1]; }
            #pragma unroll
            for (int tt = 0; tt < 4; tt++) {
                v8us au = *(v8us*)&af[tt];
                v8us ou;
                #pragma unroll
                for (int j = 0; j < 8; j++) {
                    float h = bf2f(au[j]);
                    ou[j] = f2bf(fmaxf(fmaf(cav[j], h, ccv[j]), 0.f));
                }
                af[tt] = *(v8bf*)&ou;
            }
        }
        #pragma unroll
        for (int mt = 0; mt < 4; mt++)
            #pragma unroll
            for (int nt = 0; nt < 4; nt++)
                acc[mt][nt] = __builtin_amdgcn_mfma_f32_16x16x32_bf16(
                    af[mt], bfr[nt], acc[mt][nt], 0, 0, 0);
        if (t == nk - 1) break;
        BARRIER();                        // all waves done reading buf[t&1]
        if (t + 2 < nk) {
            int kl = (t + 2) * 32;
            #pragma unroll
            for (int j = 0; j < 2; j++) {
                async16(aA[j] + kl, &As[t & 1][aoff[j]]);
                async16(aB[j] + kl, &Bs[t & 1][aoff[j]]);
            }
            VMWAIT4();                    // drain tile t+1; t+2 stays in flight
        } else {
            VMWAIT0();                    // last prefetch: drain tile t+1
        }
        BARRIER();                        // everyone's tile t+1 DMA visible
    }

    // epilogue: bias (+ lazy-BN residual) -> bf16 store + fused column stats
    const int mlim = M - m0;
    float s_sum[4] = {0.f, 0.f, 0.f, 0.f}, s_sq[4] = {0.f, 0.f, 0.f, 0.f};
    #pragma unroll
    for (int nt = 0; nt < 4; nt++) {
        int colg = n0 + wn * 64 + nt * 16 + l15;
        float bia = bias[colg];
        float rca = 0.f, rcc = 0.f;
        if (RES) { rca = r_ca[colg]; rcc = r_cc[colg]; }
        #pragma unroll
        for (int mt = 0; mt < 4; mt++) {
            int rbase = wm * 64 + mt * 16 + quad * 4;
            #pragma unroll
            for (int r = 0; r < 4; r++) {
                int rl = rbase + r;
                if (rl < mlim) {
                    size_t idx = (size_t)(m0 + rl) * N + colg;
                    float v = acc[mt][nt][r] + bia;
                    if (RES) v += rca * bf2f(resid[idx]) + rcc;
                    out[idx] = f2bf(v);
                    if (DO_STATS) { s_sum[nt] += v; s_sq[nt] += v * v; }
                }
            }
        }
    }
    if (DO_STATS) {
        const int rep = by & (NREP - 1);
        #pragma unroll
        for (int nt = 0; nt < 4; nt++) {
            float s = s_sum[nt], q = s_sq[nt];
            s += __shfl_xor(s, 16); q += __shfl_xor(q, 16);
            s += __shfl_xor(s, 32); q += __shfl_xor(q, 32);
            if (quad == 0) {
                int colg = n0 + wn * 64 + nt * 16 + l15;
                atomicAdd(&sums[rep * N + colg], s);
                atomicAdd(&sumsq[rep * N + colg], q);
            }
        }
    }
}

extern "C" void kernel_launch(void* const* d_in, const int* in_sizes, int n_in,
                              void* d_out, int out_size, void* d_ws, size_t ws_size,
                              hipStream_t stream) {
    const float* pre   = (const float*)d_in[0];
    const int*   ei    = (const int*)d_in[1];
    const float* W0    = (const float*)d_in[2];
    const float* b0    = (const float*)d_in[3];
    const float* W1    = (const float*)d_in[4];
    const float* b1    = (const float*)d_in[5];
    const float* g1    = (const float*)d_in[6];
    const float* beta1 = (const float*)d_in[7];
    const float* W2    = (const float*)d_in[8];
    const float* b2    = (const float*)d_in[9];
    const float* gf    = (const float*)d_in[10];
    const float* betaf = (const float*)d_in[11];

    char* p = (char*)d_ws;
    ushort_t* preb = (ushort_t*)p; p += (size_t)M_PAD * DIN * 2;
    ushort_t* ACT1 = (ushort_t*)p; p += (size_t)M_PAD * DD * 2;
    ushort_t* ACT2 = (ushort_t*)p; p += (size_t)M_PAD * DD * 2;
    ushort_t* H1   = (ushort_t*)p; p += (size_t)M_PAD * D2 * 2;
    ushort_t* W0T  = (ushort_t*)p; p += (size_t)DIN * DD * 2;
    ushort_t* W1T  = (ushort_t*)p; p += (size_t)NLAYERS * DD * D2 * 2;
    ushort_t* W2T  = (ushort_t*)p; p += (size_t)NLAYERS * D2 * DD * 2;
    // stats replica slabs — must stay contiguous (prep zeroes them as one range)
    float* sums1  = (float*)p; p += (size_t)NREP * D2 * 4;
    float* sumsq1 = (float*)p; p += (size_t)NREP * D2 * 4;
    float* sumsF  = (float*)p; p += (size_t)NREP * DD * 4;
    float* sumsqF = (float*)p; p += (size_t)NREP * DD * 4;
    float* ca1    = (float*)p; p += D2 * 4;
    float* cc1    = (float*)p; p += D2 * 4;
    float* caf    = (float*)p; p += DD * 4;
    float* ccf    = (float*)p; p += DD * 4;
    float2* cacc1 = (float2*)p; p += D2 * 8;
    int* deg    = (int*)p; p += (size_t)MNODES * 4;
    int* rowptr = (int*)p; p += (size_t)(MNODES + 1) * 4;
    int* cursor = (int*)p; p += (size_t)MNODES * 4;
    int* colx   = (int*)p; p += (size_t)NEDGES * 4;
    int* bsum   = (int*)p; p += 256 * 4;

    dim3 blk(256);
    const int mb = (MNODES + 127) / 128;        // 391
    const int nsb = (MNODES + 255) / 256;       // 196

    const int prep_total = R0 + RW + 256 + NSTATZ + MNODES;
    k_prep_all<<<(prep_total + 255) / 256, blk, 0, stream>>>(
        pre, preb, W0, W1, W2, W0T, W1T, W2T, caf, ccf, sums1, deg);

    k_hist<<<(NEDGES + 255) / 256, blk, 0, stream>>>(ei, deg);
    k_scan1<<<nsb, blk, 0, stream>>>(deg, rowptr, bsum, MNODES);
    k_scan2<<<1, blk, 0, stream>>>(bsum, nsb);
    k_scan3<<<nsb, blk, 0, stream>>>(deg, bsum, rowptr, cursor, MNODES);
    k_fill<<<(NEDGES + 255) / 256, blk, 0, stream>>>(ei, cursor, colx);

    // X0 = pre @ W0 + b0  -> ACT2
    k_gemm_bf<0, 0, 0><<<dim3(DD / 128, mb), blk, 0, stream>>>(
        preb, W0T, b0, nullptr, nullptr, nullptr, nullptr,
        ACT2, nullptr, nullptr, MNODES, DIN, DD);

    for (int l = 0; l < NLAYERS; l++) {
        // ACT1 = caf*(ACT2[n] + sum ACT2[src]) + (deg+1)*ccf
        k_gather<<<(MNODES + 3) / 4, blk, 0, stream>>>(rowptr, colx, ACT2, caf, ccf, ACT1);

        // H1 = ACT1 @ W1 + b1 (raw, pre-BN), fused column stats
        k_gemm_bf<1, 0, 0><<<dim3(D2 / 128, mb), blk, 0, stream>>>(
            ACT1, W1T + (size_t)l * DD * D2, b1 + (size_t)l * D2,
            nullptr, nullptr, nullptr, nullptr,
            H1, sums1, sumsq1, MNODES, DD, D2);
        k_coeffs<<<2, blk, 0, stream>>>(sums1, sumsq1, g1 + (size_t)l * D2,
                                        beta1 + (size_t)l * D2, ca1, cc1, cacc1, D2);

        // ACT2 = relu(bn1(H1)) @ W2 + b2 + bn_prev(ACT2)
        // (BN1+ReLU fused into A-fragment path; in place; fused stats)
        k_gemm_bf<1, 1, 1><<<dim3(DD / 128, mb), blk, 0, stream>>>(
            H1, W2T + (size_t)l * D2 * DD, b2 + (size_t)l * DD,
            ACT2, caf, ccf, cacc1,
            ACT2, sumsF, sumsqF, MNODES, D2, DD);
        k_coeffs<<<1, blk, 0, stream>>>(sumsF, sumsqF, gf + (size_t)l * DD,
                                        betaf + (size_t)l * DD, caf, ccf, nullptr, DD);
    }

    // d_out = caf*ACT2 + ccf  (fp32)
    k_apply_out<<<(MNODES * 64 + 255) / 256, blk, 0, stream>>>(ACT2, caf, ccf, (float*)d_out);
}